// Round 4
// baseline (127.972 us; speedup 1.0000x reference)
//
#include <hip/hip_runtime.h>

// Unfold (im2col) x: [16, 64, 128, 128] f32, K=3, pad=1.
// out[(b*64+c)*9 + m][y][x] = in[b,c, y + m/3 - 1, x + m%3 - 1], 0 if OOB.
// Write-BW-bound: 604 MB out + 64 MB in (L3-resident on replay).
// R4: per di, stage 8 row-groups in registers, then store each dj-plane as a
// sequential burst -> 1 write stream per wave at a time (was 9 concurrent).

typedef float f32x4 __attribute__((ext_vector_type(4)));

__global__ __launch_bounds__(256) void unfold_kernel(
    const float* __restrict__ in, float* __restrict__ out) {
    constexpr int H = 128, W = 128;
    constexpr int W4 = W / 4;         // 32 float4 per row
    constexpr int PLANE4 = H * W / 4; // 4096 float4 per plane

    const int blk = blockIdx.x;      // 0 .. 2047
    const int half = blk & 1;
    const int bc = blk >> 1;         // b*64 + c

    const float* plane_in = in + (size_t)bc * (H * W);
    f32x4* plane_out = reinterpret_cast<f32x4*>(out) + (size_t)bc * 9 * PLANE4;

    const int tid = threadIdx.x;
    const int xq = tid & (W4 - 1);   // 0..31
    const int r0 = tid >> 5;         // 0..7
    const int x0 = xq << 2;
    const int rbase = half * 64 + r0;

    #pragma unroll
    for (int di = -1; di <= 1; ++di) {
        f32x4 a[8];
        float lf[8], rt[8];
        #pragma unroll
        for (int g = 0; g < 8; ++g) {
            const int ry = rbase + g * 8 + di;
            a[g] = (f32x4)(0.f); lf[g] = 0.f; rt[g] = 0.f;
            if ((unsigned)ry < (unsigned)H) {
                const float* row = plane_in + ry * W;
                a[g] = reinterpret_cast<const f32x4*>(row)[xq];
                if (x0 > 0)     lf[g] = row[x0 - 1];
                if (x0 < W - 4) rt[g] = row[x0 + 4];
            }
        }
        const int mbase = (di + 1) * 3;
        f32x4* p0 = plane_out + (size_t)(mbase + 0) * PLANE4;
        f32x4* p1 = plane_out + (size_t)(mbase + 1) * PLANE4;
        f32x4* p2 = plane_out + (size_t)(mbase + 2) * PLANE4;
        #pragma unroll
        for (int g = 0; g < 8; ++g) {        // dj = -1 burst
            const size_t o = (size_t)(rbase + g * 8) * W4 + xq;
            f32x4 v; v.x = lf[g]; v.y = a[g].x; v.z = a[g].y; v.w = a[g].z;
            __builtin_nontemporal_store(v, &p0[o]);
        }
        #pragma unroll
        for (int g = 0; g < 8; ++g) {        // dj = 0 burst
            const size_t o = (size_t)(rbase + g * 8) * W4 + xq;
            __builtin_nontemporal_store(a[g], &p1[o]);
        }
        #pragma unroll
        for (int g = 0; g < 8; ++g) {        // dj = +1 burst
            const size_t o = (size_t)(rbase + g * 8) * W4 + xq;
            f32x4 v; v.x = a[g].y; v.y = a[g].z; v.z = a[g].w; v.w = rt[g];
            __builtin_nontemporal_store(v, &p2[o]);
        }
    }
}

extern "C" void kernel_launch(void* const* d_in, const int* in_sizes, int n_in,
                              void* d_out, int out_size, void* d_ws, size_t ws_size,
                              hipStream_t stream) {
    const float* in = (const float*)d_in[0];
    float* out = (float*)d_out;
    // 16*64 planes x 2 halves = 2048 blocks, 256 threads each.
    unfold_kernel<<<2048, 256, 0, stream>>>(in, out);
}

// Round 5
// 113.134 us; speedup vs baseline: 1.1312x; 1.1312x over previous
//
#include <hip/hip_runtime.h>

// Unfold (im2col) x: [16, 64, 128, 128] f32, K=3, pad=1.
// out[(b*64+c)*9 + m][y][x] = in[b,c, y + m/3 - 1, x + m%3 - 1], 0 if OOB.
// R5: R3 interleaved structure (won vs R4 bursts), but edge values via
// 32-wide wave shuffles instead of scalar global loads: vmem 18 -> 12 per
// 9 output float4s. Row = 32 lanes x float4, shifts never cross the group.

typedef float f32x4 __attribute__((ext_vector_type(4)));

__global__ __launch_bounds__(256) void unfold_kernel(
    const float* __restrict__ in, float* __restrict__ out) {
    constexpr int H = 128, W = 128;
    constexpr int W4 = W / 4;         // 32 float4 per row
    constexpr int PLANE4 = H * W / 4; // 4096 float4 per plane

    const int blk = blockIdx.x;      // 0 .. 2047
    const int half = blk & 1;
    const int bc = blk >> 1;         // b*64 + c

    const float* plane_in = in + (size_t)bc * (H * W);
    f32x4* plane_out = reinterpret_cast<f32x4*>(out) + (size_t)bc * 9 * PLANE4;

    const int tid = threadIdx.x;
    const int xq = tid & (W4 - 1);   // 0..31
    const int r0 = tid >> 5;         // 0..7

    for (int g = 0; g < 8; ++g) {             // 8 groups x 8 rows = 64 rows
        const int r = half * 64 + g * 8 + r0; // output row
        #pragma unroll
        for (int di = -1; di <= 1; ++di) {
            const int ry = r + di;
            f32x4 a = (f32x4)(0.f);
            if ((unsigned)ry < (unsigned)H) {
                a = reinterpret_cast<const f32x4*>(plane_in + ry * W)[xq];
            }
            // edge values from neighbor lanes within the 32-lane row group
            float left  = __shfl_up(a.w, 1, 32);
            float right = __shfl_down(a.x, 1, 32);
            if (xq == 0)      left  = 0.f;   // x = -1 pad
            if (xq == W4 - 1) right = 0.f;   // x = 128 pad
            f32x4 vm1; vm1.x = left; vm1.y = a.x; vm1.z = a.y; vm1.w = a.z; // dj=-1
            f32x4 vp1; vp1.x = a.y; vp1.y = a.z; vp1.z = a.w; vp1.w = right; // dj=+1
            const int mbase = (di + 1) * 3;
            const size_t o = (size_t)r * W4 + xq;
            __builtin_nontemporal_store(vm1, &plane_out[(size_t)(mbase + 0) * PLANE4 + o]);
            __builtin_nontemporal_store(a,   &plane_out[(size_t)(mbase + 1) * PLANE4 + o]);
            __builtin_nontemporal_store(vp1, &plane_out[(size_t)(mbase + 2) * PLANE4 + o]);
        }
    }
}

extern "C" void kernel_launch(void* const* d_in, const int* in_sizes, int n_in,
                              void* d_out, int out_size, void* d_ws, size_t ws_size,
                              hipStream_t stream) {
    const float* in = (const float*)d_in[0];
    float* out = (float*)d_out;
    // 16*64 planes x 2 halves = 2048 blocks, 256 threads each.
    unfold_kernel<<<2048, 256, 0, stream>>>(in, out);
}